// Round 12
// baseline (291.881 us; speedup 1.0000x reference)
//
#include <hip/hip_runtime.h>

// MHSA matched-filter encode, bit-exact replication of the fp32 reference.
// 1 row per wave; window element j on lane (tid&15), replicated x4.
// Wall time = 2048 x per-step dependency chain (512 waves co-resident,
// 1 wave/SIMD -> every dependent latency and branch bubble is exposed).
//
// Round-9 = round-5's W=4 speculative core (bit-exact, absmax 0 in r5)
//         + round-8's PIN4 pinned chunk-ahead prefetch (proven: r8 took
//           ds_read off the chain) + branchless obits + cold tail hint.
// History: r4 serial links+per-step ds = 161 cyc/step; r5 spec core but
// prefetch sunk to use (exposed ~120 cyc ds) = 289; r8 pinned prefetch,
// serial links = 146. This combines the two proven halves.
//
// Exactness: every window value is produced by the same repeated fp32
// subtractions as the reference (speculative state w_r = r subs, used only
// when cond_{r-1} held); err is the literal sequential fp32 prefix;
// fmax(f-d,0) is bit-equivalent to where(d<f, f-d, 0) (+/-0 neutral when
// added to err >= +0); first-crossing selects use the monotone cond chain
// k1>=k2>=k3 so v ends as w_{alive_count} exactly.

constexpr int NN = 2048;   // row length
constexpr int NBLK = 512;  // rows

__device__ __forceinline__ float f_readlane(float v, int lane) {
    return __int_as_float(__builtin_amdgcn_readlane(__float_as_int(v), lane));
}

// Slide window one toward lane 0: lane i <- lane i+1 within each 16-lane DPP
// row (row_shl:1); lane 15 (invalid source, bound_ctrl=false) keeps `fill`.
__device__ __forceinline__ float f_slide(float src, float fill) {
    return __int_as_float(__builtin_amdgcn_update_dpp(
        __float_as_int(fill), __float_as_int(src),
        0x101 /* row_shl:1 */, 0xF, 0xF, false));
}

// Force 4x float4 to be materialized in VGPRs HERE (defeats load sinking).
#define PIN4(a, b, c, d)                                                   \
    asm volatile("" : "+v"(a.x), "+v"(a.y), "+v"(a.z), "+v"(a.w),          \
                      "+v"(b.x), "+v"(b.y), "+v"(b.z), "+v"(b.w),          \
                      "+v"(c.x), "+v"(c.y), "+v"(c.z), "+v"(c.w),          \
                      "+v"(d.x), "+v"(d.y), "+v"(d.z), "+v"(d.w))

__global__ __launch_bounds__(64) void mhsa_kernel(const float* __restrict__ data,
                                                  const float* __restrict__ filt,
                                                  float* __restrict__ out) {
    __shared__ float lrow[NN + 32];  // +32: last chunk's prefetch overruns
    const int row = blockIdx.x;
    const int tid = threadIdx.x;
    const int j = tid & 15;

    const float* rp = data + (size_t)row * NN;
    float* op = out + (size_t)row * NN;

    // Stage row into LDS (read-only thereafter; window state lives in regs).
    const float4* rp4 = (const float4*)rp;
    float4* l4 = (float4*)lrow;
#pragma unroll
    for (int k = 0; k < NN / 4 / 64; ++k)  // 8 x float4 per thread
        l4[tid + 64 * k] = rp4[tid + 64 * k];
    if (tid < 8) l4[NN / 4 + tid] = make_float4(0.f, 0.f, 0.f, 0.f);  // pad
    __syncthreads();

    const float fv = filt[j] * 0.2f;  // f = filter * NEW_AMP (exact, 1 mul)
    float v = lrow[j];                // window element j at step i=0

    // Current chunk's 16 injection elements (row[16..31]), pinned in regs.
    float4 n0 = l4[4], n1 = l4[5], n2 = l4[6], n3 = l4[7];
    PIN4(n0, n1, n2, n3);

    for (int ib = 0; ib < NN - 16; ib += 16) {
        // Prefetch NEXT chunk's injection elements (row[ib+32 .. ib+47]);
        // pinned so the ds_reads issue and complete here, off the chain.
        const float4* pf = (const float4*)(lrow + ib + 32);
        float4 p0 = pf[0], p1 = pf[1], p2 = pf[2], p3 = pf[3];
        PIN4(p0, p1, p2, p3);

        unsigned obits = 0;
#pragma unroll
        for (int s = 0; s < 16; ++s) {
            // Static (post-unroll) component pick of this step's fill value.
            const float4 q = (s < 4) ? n0 : (s < 8) ? n1 : (s < 12) ? n2 : n3;
            const int c = s & 3;
            const float nxt = (c == 0) ? q.x : (c == 1) ? q.y
                            : (c == 2) ? q.z : q.w;

            // W=4 speculation: states w_r (r repeated subs) and diagonal
            // terms t_r in parallel per-lane chains; err prefix via 3
            // parallel readlanes + serial adds (literal reference order).
            float w1 = v - fv;
            float w2 = w1 - fv;
            float w3 = w2 - fv;
            float t0 = fmaxf(fv - v, 0.0f);
            float t1 = fmaxf(fv - w1, 0.0f);
            float t2 = fmaxf(fv - w2, 0.0f);
            float t3 = fmaxf(fv - w3, 0.0f);
            float e0 = f_readlane(t0, 0);
            float e1 = e0 + f_readlane(t1, 1);
            float e2 = e1 + f_readlane(t2, 2);
            float e3 = e2 + f_readlane(t3, 3);
            const bool k1 = (e0 <= 0.5f);  // cond_0 == out[i]; k1>=k2>=k3
            const bool k2 = (e1 <= 0.5f);
            const bool k3 = (e2 <= 0.5f);
            obits |= k1 ? (1u << s) : 0u;  // branchless

            if (__builtin_expect(e3 <= 0.5f, 0)) {
                // >=4 alive iterations (rare): continue exactly, serial.
                v = w3;
                float err = e3;
#pragma unroll 1
                for (int r = 4; r <= 16; ++r) {
                    v = v - fv;          // decrement #r (prev cond true)
                    if (r == 16) break;  // j=15 cond true: decrement only
                    float tr = fmaxf(fv - v, 0.0f);
                    err += f_readlane(tr, r);
                    if (!(err <= 0.5f)) break;
                }
            } else {
                // First crossing within 0..3: monotone conds pick w_{alive}.
                v = k1 ? w1 : v;
                v = k2 ? w2 : v;
                v = k3 ? w3 : v;
            }
            v = f_slide(v, nxt);  // window <- row[i+1 .. i+16]
        }
        // 16 outputs; replica groups store duplicates (benign).
        op[ib + j] = ((obits >> j) & 1u) ? 1.0f : 0.0f;

        n0 = p0; n1 = p1; n2 = p2; n3 = p3;
    }

    // Step i = 2032 (last fits step): output only, state never read again.
    {
        float t = fmaxf(fv - v, 0.0f);
        float v0 = (f_readlane(t, 0) <= 0.5f) ? 1.0f : 0.0f;
        // i = 2033..2047: fits=false -> err stays 0 -> out = 1.
        op[(NN - 16) + j] = (j == 0) ? v0 : 1.0f;
    }
}

extern "C" void kernel_launch(void* const* d_in, const int* in_sizes, int n_in,
                              void* d_out, int out_size, void* d_ws, size_t ws_size,
                              hipStream_t stream) {
    const float* data = (const float*)d_in[0];  // [512, 2048] f32
    const float* filt = (const float*)d_in[1];  // [16] f32
    float* out = (float*)d_out;                 // [512, 2048] f32
    (void)in_sizes; (void)n_in; (void)out_size; (void)d_ws; (void)ws_size;
    mhsa_kernel<<<dim3(NBLK), dim3(64), 0, stream>>>(data, filt, out);
}

// Round 13
// 166.567 us; speedup vs baseline: 1.7523x; 1.7523x over previous
//
#include <hip/hip_runtime.h>

// MHSA matched-filter encode, bit-exact replication of the fp32 reference.
// 1 row per wave; window element j on lane (tid&15), replicated x4.
// Wall = 2048 x per-step dependency chain. r8 (adaptive serial links,
// 146 cyc/step) is the proven best; W=4 branchless spec measured ~283
// cyc/step twice (r5, r12) and is abandoned.
//
// Round-13 deltas vs r8 (all value-identical transforms):
//  - maxless link0: cond_0 = (fl(fv-v) <= 0.5) directly (raw <= 0 cases
//    coincide with term==0 => e0=0 <= 0.5; positive raw == e0 exactly).
//    err seed = fmaxf(readlane(t),0) — same value, max after readlane.
//  - speculative slide: vs = slide(v,nxt), ts = fv - vs kept current
//    inside the link loop (independent of the readlane chain -> fills
//    stalls); step exit carries (v,t) = (vs,ts), removing slide+sub from
//    the inter-step critical chain.
//  - t carried across steps and chunks.
// Kept from r8: PIN4 pinned chunk-ahead prefetch, ballot entry test,
// branch-guarded serial link loop (the adaptive predication).

constexpr int NN = 2048;   // row length
constexpr int NBLK = 512;  // rows

__device__ __forceinline__ float f_readlane(float v, int lane) {
    return __int_as_float(__builtin_amdgcn_readlane(__float_as_int(v), lane));
}

// Slide window one toward lane 0: lane i <- lane i+1 within each 16-lane DPP
// row (row_shl:1); lane 15 (invalid source, bound_ctrl=false) keeps `fill`.
__device__ __forceinline__ float f_slide(float src, float fill) {
    return __int_as_float(__builtin_amdgcn_update_dpp(
        __float_as_int(fill), __float_as_int(src),
        0x101 /* row_shl:1 */, 0xF, 0xF, false));
}

// Force 4x float4 to be materialized in VGPRs HERE (defeats load sinking).
#define PIN4(a, b, c, d)                                                   \
    asm volatile("" : "+v"(a.x), "+v"(a.y), "+v"(a.z), "+v"(a.w),          \
                      "+v"(b.x), "+v"(b.y), "+v"(b.z), "+v"(b.w),          \
                      "+v"(c.x), "+v"(c.y), "+v"(c.z), "+v"(c.w),          \
                      "+v"(d.x), "+v"(d.y), "+v"(d.z), "+v"(d.w))

__global__ __launch_bounds__(64) void mhsa_kernel(const float* __restrict__ data,
                                                  const float* __restrict__ filt,
                                                  float* __restrict__ out) {
    __shared__ float lrow[NN + 32];  // +32: last chunk's prefetch overruns
    const int row = blockIdx.x;
    const int tid = threadIdx.x;
    const int j = tid & 15;

    const float* rp = data + (size_t)row * NN;
    float* op = out + (size_t)row * NN;

    // Stage row into LDS (read-only thereafter; window state lives in regs).
    const float4* rp4 = (const float4*)rp;
    float4* l4 = (float4*)lrow;
#pragma unroll
    for (int k = 0; k < NN / 4 / 64; ++k)  // 8 x float4 per thread
        l4[tid + 64 * k] = rp4[tid + 64 * k];
    if (tid < 8) l4[NN / 4 + tid] = make_float4(0.f, 0.f, 0.f, 0.f);  // pad
    __syncthreads();

    const float fv = filt[j] * 0.2f;  // f = filter * NEW_AMP (exact, 1 mul)
    float v = lrow[j];                // window element j at step i=0
    float t = fv - v;                 // carried raw link-0 term argument

    // Current chunk's 16 injection elements (row[16..31]), pinned in regs.
    float4 n0 = l4[4], n1 = l4[5], n2 = l4[6], n3 = l4[7];
    PIN4(n0, n1, n2, n3);

    for (int ib = 0; ib < NN - 16; ib += 16) {
        // Prefetch NEXT chunk's injection elements (row[ib+32 .. ib+47]).
        const float4* pf = (const float4*)(lrow + ib + 32);
        float4 p0 = pf[0], p1 = pf[1], p2 = pf[2], p3 = pf[3];
        PIN4(p0, p1, p2, p3);

        unsigned obits = 0;
#pragma unroll
        for (int s = 0; s < 16; ++s) {
            // Static (post-unroll) component pick of this step's fill value.
            const float4 q = (s < 4) ? n0 : (s < 8) ? n1 : (s < 12) ? n2 : n3;
            const int c = s & 3;
            const float nxt = (c == 0) ? q.x : (c == 1) ? q.y
                            : (c == 2) ? q.z : q.w;

            // Speculative next-step carry (c=0 case); independent of the
            // ballot/readlane chain below -> fills its stall slots.
            float vs = f_slide(v, nxt);
            float ts = fv - vs;

            // Link 0: cond_0 = (raw t on lane 0) <= 0.5 == (e0 <= 0.5).
            if (__ballot(t <= 0.5f) & 1ull) {
                obits |= (1u << s);
                float err = fmaxf(f_readlane(t, 0), 0.0f);  // e0 exactly
#pragma unroll
                for (int r = 1; r <= 16; ++r) {
                    v = v - fv;            // decrement #r (prev cond true)
                    vs = f_slide(v, nxt);  // keep speculation current
                    ts = fv - vs;
                    if (r == 16) break;    // j=15 cond true: decrement only
                    float tr = fmaxf(fv - v, 0.0f);
                    err += f_readlane(tr, r);
                    if (!(err <= 0.5f)) break;
                }
            }
            v = vs;  // window <- row[i+1 .. i+16]
            t = ts;  // next step's link-0 argument, already computed
        }
        // 16 outputs; replica groups store duplicates (benign).
        op[ib + j] = ((obits >> j) & 1u) ? 1.0f : 0.0f;

        n0 = p0; n1 = p1; n2 = p2; n3 = p3;
    }

    // Step i = 2032 (last fits step): carried t == fv - v for this window.
    {
        float v0 = (__ballot(t <= 0.5f) & 1ull) ? 1.0f : 0.0f;
        // i = 2033..2047: fits=false -> err stays 0 -> out = 1.
        op[(NN - 16) + j] = (j == 0) ? v0 : 1.0f;
    }
}

extern "C" void kernel_launch(void* const* d_in, const int* in_sizes, int n_in,
                              void* d_out, int out_size, void* d_ws, size_t ws_size,
                              hipStream_t stream) {
    const float* data = (const float*)d_in[0];  // [512, 2048] f32
    const float* filt = (const float*)d_in[1];  // [16] f32
    float* out = (float*)d_out;                 // [512, 2048] f32
    (void)in_sizes; (void)n_in; (void)out_size; (void)d_ws; (void)ws_size;
    mhsa_kernel<<<dim3(NBLK), dim3(64), 0, stream>>>(data, filt, out);
}